// Round 1
// baseline (210.897 us; speedup 1.0000x reference)
//
#include <hip/hip_runtime.h>
#include <math.h>

#define LL 128
#define TT 11
#define NP 121            // T*T (y, y_prev) pairs
#define KK 7
#define GS 20             // sp group stride (floats); group g at [g*20 .. g*20+10], pad at +11
#define SPW 240           // 11 groups*20 + dummy slots 220..226
#define NSLOT 8           // E-pane LDS ring slots
#define PANEF 1024        // floats per E pane: 2 halves x 128 pairs x 4

#define LOG2E 1.4426950408889634f
#define LN2   0.6931471805599453f
#define NEG2  (-10000.0f * LOG2E)   // ref NEG in base-2 domain
#define MASK2 (-1.0e9f)             // masked -> exp2 underflows to exactly 0

typedef const __attribute__((address_space(1))) unsigned int* gas_t;
typedef __attribute__((address_space(3)))       unsigned int* las_t;

__device__ __forceinline__ float fast_exp2(float x) { return __builtin_amdgcn_exp2f(x); }
__device__ __forceinline__ float fast_log2(float x) { return __builtin_amdgcn_logf(x); }
#if __has_builtin(__builtin_amdgcn_rcpf)
__device__ __forceinline__ float fast_rcp(float x) { return __builtin_amdgcn_rcpf(x); }
#else
__device__ __forceinline__ float fast_rcp(float x) { return 1.0f / x; }
#endif
__device__ __forceinline__ float rfl(float x) {
    return __int_as_float(__builtin_amdgcn_readfirstlane(__float_as_int(x)));
}
__device__ __forceinline__ void cfence() { __builtin_amdgcn_wave_barrier(); }
#define VMWAIT20() asm volatile("s_waitcnt vmcnt(20)" ::: "memory")
#define VMWAIT0()  asm volatile("s_waitcnt vmcnt(0)"  ::: "memory")

// ---------------------------------------------------------------------------
// Prep: E pane for (b, i) holds exp2(scores[b][j][i-1][yp][y]*LOG2E) for the
// K=7 window j = i-7+k (0 when j<0 / o>=121 / k==7), o = y*11+yp.
//
// SPLIT-PANE LAYOUT (this round's change): pane = [m=2][pair o=128][float4],
// m=0 -> vals[0..3], m=1 -> vals[4..7]. All dp-side ds_read_b128 of E become
// stride-16B contiguous (conflict-free; the old [o][8] layout was stride-32B
// -> only 16/32 banks active, ~2x DS pipe occupancy per read). Prep stores
// also become stride-16 fully coalesced.
// ---------------------------------------------------------------------------
__global__ __launch_bounds__(256) void hscrf_prep(const float* __restrict__ scores,
                                                  float* __restrict__ E,
                                                  int n_batch)
{
    const int idx = blockIdx.x * blockDim.x + threadIdx.x;   // (b, pi, o)
    if (idx >= n_batch * LL * 128) return;
    const int o  = idx & 127;
    const int pi = (idx >> 7) & (LL - 1);   // pi = i-1
    const int b  = idx >> 14;

    float vals[8];
#pragma unroll
    for (int k = 0; k < 8; ++k) vals[k] = 0.0f;

    if (o < NP) {
        const int y = o / TT, yp = o % TT;
        const float* sb = scores + (size_t)b * (size_t)(LL * LL * NP);
#pragma unroll
        for (int k = 0; k < KK; ++k) {
            const int j = (pi + 1) - KK + k;
            if (j >= 0) {
                const float sc = sb[((size_t)j * LL + pi) * NP + yp * TT + y];
                vals[k] = fast_exp2(sc * LOG2E);
            }
        }
    }
    // split-pane store: m=0 block at [0..127], m=1 block at [128..255] (float4 units)
    float4* dst = (float4*)(E + ((size_t)b * LL + pi) * PANEF);
    dst[o]       = make_float4(vals[0], vals[1], vals[2], vals[3]);
    dst[128 + o] = make_float4(vals[4], vals[5], vals[6], vals[7]);
}

// ---------------------------------------------------------------------------
// DP: one wave per CU. Linear-domain window W[k][yp] = exp2(alpha2[row]-C):
// phase 1 is 7 FMAs (E from the LDS ring), phase 2 is the usual sp round-trip
// add tree, then W' = shift*r with r = rcp(S(0)) -- ZERO transcendentals on
// the serial chain. C (running log2 scale) is maintained off-chain for the
// final readout. E panes stream in via 4x width-16 global_load_lds per pane
// (compiler-proof prefetch), lead 5 steps, s_waitcnt vmcnt(20) per step.
// E reads are stride-16 conflict-free thanks to the split-pane layout.
// ---------------------------------------------------------------------------
__global__ __launch_bounds__(64, 1) void hscrf_dp(const float* __restrict__ E,
                                                  const int* __restrict__ mask,
                                                  float* __restrict__ out,
                                                  int n_batch)
{
    const int l = threadIdx.x;
    const int b = blockIdx.x;
    if (b >= n_batch) return;

    __shared__ __align__(64) float ring[NSLOT][PANEF];   // 32 KB
    __shared__ __align__(64) float sp[SPW];

    const int o1  = l + 64;
    const int o1c = (o1 < NP) ? o1 : 0;
    const int y0 = l / TT,   yp0 = l % TT;
    const int y1 = o1c / TT, yp1 = o1c % TT;
    const int i0w = y0 * GS + yp0;                        // phase-1 write slots
    const int i1w = (o1 < NP) ? (y1 * GS + yp1) : (220 + (l - 57));

    if (l < TT) sp[l * GS + 11] = 0.0f;                   // zero pad slot for b128 phase-2

    const int mb = mask[b];
    const float* Ebase = E + (size_t)b * (size_t)(LL * PANEF);

    // DMA pane i (floats (i-1)*1024 .. +1023) into ring slot i&7.
    // 4 ops x (64 lanes x 16 B). LDS dest is wave-uniform; HW adds lane*16.
    auto dma_pane = [&](int i) {
        const int slot = i & (NSLOT - 1);
        const float* src = Ebase + (size_t)(i - 1) * PANEF;
#pragma unroll
        for (int m = 0; m < 4; ++m)
            __builtin_amdgcn_global_load_lds((gas_t)(src + m * 256 + l * 4),
                                             (las_t)&ring[slot][m * 256], 16, 0, 0);
    };

    // Linear-domain windows. Row 0: start state (yp==10) = 1, others 0
    // (= exp2(NEG) which underflows to 0 in fp32, same as the reference).
    float W0[KK], W1[KK];
#pragma unroll
    for (int k = 0; k < KK; ++k) { W0[k] = 0.0f; W1[k] = 0.0f; }
    W0[KK - 1] = (yp0 == TT - 1) ? 1.0f : 0.0f;
    W1[KK - 1] = (yp1 == TT - 1) ? 1.0f : 0.0f;

    float Cc = 0.0f;       // running log2 scale: alpha2[i][y] = Cc + log2(S_i(y))
    float saved = 0.0f;

    // Prologue: panes 1..6 in flight (24 ops); wait to 20 -> pane 1 complete.
    dma_pane(1); dma_pane(2); dma_pane(3);
    dma_pane(4); dma_pane(5); dma_pane(6);
    VMWAIT20();

    // E regs for the current step (pane 1), split-pane indices (stride-16B reads).
    const float4* ep1 = (const float4*)&ring[1][0];
    float4 ea0 = ep1[l],      ea1 = ep1[128 + l];
    float4 eb0 = ep1[64 + l], eb1 = ep1[192 + l];

    auto body = [&](int i, bool main) {
        // ---- phase 1: 7 FMAs per pair (tree), sp write ----
        float p0 = fmaf(ea0.x, W0[0], ea0.y * W0[1]);
        float q0 = fmaf(ea0.z, W0[2], ea0.w * W0[3]);
        float u0 = fmaf(ea1.x, W0[4], ea1.y * W0[5]);
        float s0 = (p0 + q0) + fmaf(ea1.z, W0[6], u0);
        float p1 = fmaf(eb0.x, W1[0], eb0.y * W1[1]);
        float q1 = fmaf(eb0.z, W1[2], eb0.w * W1[3]);
        float u1 = fmaf(eb1.x, W1[4], eb1.y * W1[5]);
        float s1 = (p1 + q1) + fmaf(eb1.z, W1[6], u1);
        sp[i0w] = s0;
        sp[i1w] = s1;

        cfence();                      // DS pipe in-order per wave

        // ---- phase 2 reads (chain-critical) ----
        const float4 qa0 = *(const float4*)(sp + yp0 * GS);
        const float4 qb0 = *(const float4*)(sp + yp0 * GS + 4);
        const float4 qc0 = *(const float4*)(sp + yp0 * GS + 8);   // pad=0
        const float4 qa1 = *(const float4*)(sp + yp1 * GS);
        const float4 qb1 = *(const float4*)(sp + yp1 * GS + 4);
        const float4 qc1 = *(const float4*)(sp + yp1 * GS + 8);

        if (main) {
            dma_pane(i + 6);           // keep ring full (panes i+1..i+6 in flight)
            VMWAIT20();                // completes pane i+1; i+2..i+6 stay in flight
        }

        // ---- E for next step (latency hidden: needed only next iteration) ----
        // Split-pane layout: each ds_read_b128 below is stride-16B contiguous
        // across the wave (1 KB span, all 32 banks, conflict-free).
        const int ns = (i + 1) & (NSLOT - 1);
        const float4* ep = (const float4*)&ring[ns][0];
        const float4 na0 = ep[l],      na1 = ep[128 + l];
        const float4 nb0 = ep[64 + l], nb1 = ep[192 + l];

        // ---- phase-2 sums ----
        const float SA = (((qa0.x + qa0.y) + (qa0.z + qa0.w)) +
                          ((qb0.x + qb0.y) + (qb0.z + qb0.w))) +
                         ((qc0.x + qc0.y) + (qc0.z + qc0.w));
        const float SB = (((qa1.x + qa1.y) + (qa1.z + qa1.w)) +
                          ((qb1.x + qb1.y) + (qb1.z + qb1.w))) +
                         ((qc1.x + qc1.y) + (qc1.z + qc1.w));

        // ---- rescale: r = 1/S(0) (lane 0 has yp0==0) ----
        const float s0u = rfl(SA);
        const float r = fast_rcp(s0u);

        saved = (i == mb) ? Cc + fast_log2(SA) : saved;   // alpha2[i][yp0], off-chain
        Cc += fast_log2(s0u);                             // off-chain

#pragma unroll
        for (int k = 0; k < KK - 1; ++k) { W0[k] = W0[k + 1] * r; W1[k] = W1[k + 1] * r; }
        W0[KK - 1] = SA * r;
        W1[KK - 1] = SB * r;

        ea0 = na0; ea1 = na1; eb0 = nb0; eb1 = nb1;

        cfence();                      // order phase-2 reads before next sp writes
    };

    for (int i = 1; i <= LL - 6; ++i) body(i, true);
    VMWAIT0();                         // tail: all remaining panes complete
    for (int i = LL - 5; i <= LL; ++i) body(i, false);

    if (l == TT - 2) {                 // lane 9: yp0 == stop_id = 9
        atomicAdd(out, saved * LN2);   // back to natural log
    }
}

// ---------------------------------------------------------------------------
// Fallback (round-6 kernel, known-correct) if ws_size can't hold E.
// ---------------------------------------------------------------------------
__global__ __launch_bounds__(64, 1) void hscrf_fwd_fb(const float* __restrict__ scores,
                                                      const int* __restrict__ mask,
                                                      float* __restrict__ out,
                                                      int n_batch)
{
    const int l = threadIdx.x;
    const int b = blockIdx.x;
    if (b >= n_batch) return;

    __shared__ __align__(64) float sp[SPW];

    const int o1  = l + 64;
    const int o1c = (o1 < NP) ? o1 : 0;
    const int y0 = l / TT,   yp0 = l % TT;
    const int y1 = o1c / TT, yp1 = o1c % TT;
    const int e0 = yp0 * TT + y0;
    const int e1 = yp1 * TT + y1;
    const int i0w = y0 * GS + yp0;
    const int i1w = (o1 < NP) ? (y1 * GS + yp1) : (220 + (l - 57));

    if (l < TT) sp[l * GS + 11] = 0.0f;

    const int mb = mask[b];
    const float* sb = scores + (size_t)b * (size_t)(LL * LL * NP);

    float win0[KK], win1[KK];
#pragma unroll
    for (int k = 0; k < KK; ++k) { win0[k] = MASK2; win1[k] = MASK2; }
    float na0 = (yp0 == TT - 1) ? 0.0f : NEG2;
    float na1 = (yp1 == TT - 1) ? 0.0f : NEG2;

    float C  = 0.0f, Cn = 0.0f, pp0 = 0.0f, pp1 = 0.0f, saved = 0.0f;

    float cA0[KK], cA1[KK], cB0[KK], cB1[KK];
    float cC0[KK], cC1[KK], cD0[KK], cD1[KK];

    auto load_pane = [&](int i, float (&c0)[KK], float (&c1)[KK]) {
#pragma unroll
        for (int k = 0; k < KK; ++k) {
            int j = i - KK + k;
            int jc = j < 0 ? 0 : j;
            const size_t base = ((size_t)jc * LL + (size_t)(i - 1)) * NP;
            c0[k] = sb[base + e0];
            c1[k] = sb[base + e1];
        }
    };

    load_pane(1, cA0, cA1); load_pane(2, cB0, cB1);
    load_pane(3, cC0, cC1); load_pane(4, cD0, cD1);

    auto step = [&](int i, float (&c0)[KK], float (&c1)[KK],
                    float (&n0)[KK], float (&n1)[KK]) {
#pragma unroll
        for (int k = 0; k < KK - 1; ++k) { win0[k] = win0[k + 1]; win1[k] = win1[k + 1]; }
        win0[KK - 1] = na0;
        win1[KK - 1] = na1;

        const float g0 = fast_exp2(fmaf(c0[KK - 1], LOG2E, win0[KK - 1]) - C);
        const float g1 = fast_exp2(fmaf(c1[KK - 1], LOG2E, win1[KK - 1]) - C);
        sp[i0w] = pp0 + g0;
        sp[i1w] = pp1 + g1;

        if (i + 4 <= LL) load_pane(i + 4, c0, c1);

        cfence();

        const float4 qa0 = *(const float4*)(sp + yp0 * GS);
        const float4 qb0 = *(const float4*)(sp + yp0 * GS + 4);
        const float4 qc0 = *(const float4*)(sp + yp0 * GS + 8);
        const float4 qa1 = *(const float4*)(sp + yp1 * GS);
        const float4 qb1 = *(const float4*)(sp + yp1 * GS + 4);
        const float4 qc1 = *(const float4*)(sp + yp1 * GS + 8);

        float t0 = 0.0f, t1 = 0.0f;
#pragma unroll
        for (int k = 0; k < KK - 1; ++k) {
            t0 += fast_exp2(fmaf(n0[k], LOG2E, win0[k + 1]) - Cn);
            t1 += fast_exp2(fmaf(n1[k], LOG2E, win1[k + 1]) - Cn);
        }
        pp0 = t0; pp1 = t1;

        const float S0 = (((qa0.x + qa0.y) + (qa0.z + qa0.w)) +
                          ((qb0.x + qb0.y) + (qb0.z + qb0.w))) +
                         ((qc0.x + qc0.y) + (qc0.z + qc0.w));
        const float S1 = (((qa1.x + qa1.y) + (qa1.z + qa1.w)) +
                          ((qb1.x + qb1.y) + (qb1.z + qb1.w))) +
                         ((qc1.x + qc1.y) + (qc1.z + qc1.w));

        const float A0 = C + fast_log2(S0);
        const float A1 = C + fast_log2(S1);
        na0 = A0; na1 = A1;
        saved = (i == mb) ? A0 : saved;
        C  = Cn;
        Cn = rfl(A0);

        cfence();
    };

    for (int i = 1; i <= LL; i += 4) {
        step(i,     cA0, cA1, cB0, cB1);
        step(i + 1, cB0, cB1, cC0, cC1);
        step(i + 2, cC0, cC1, cD0, cD1);
        step(i + 3, cD0, cD1, cA0, cA1);
    }

    if (l == TT - 2) atomicAdd(out, saved * LN2);
}

extern "C" void kernel_launch(void* const* d_in, const int* in_sizes, int n_in,
                              void* d_out, int out_size, void* d_ws, size_t ws_size,
                              hipStream_t stream) {
    const float* scores = (const float*)d_in[0];
    const int*   mask   = (const int*)d_in[1];
    float* out = (float*)d_out;
    const int B = in_sizes[1];   // 16

    hipMemsetAsync(out, 0, sizeof(float) * out_size, stream);

    const size_t need = (size_t)B * LL * 128 * 8 * sizeof(float);   // 8.39 MB
    if (ws_size >= need) {
        float* E = (float*)d_ws;
        const int total = B * LL * 128;
        hscrf_prep<<<(total + 255) / 256, 256, 0, stream>>>(scores, E, B);
        hscrf_dp<<<B, 64, 0, stream>>>(E, mask, out, B);
    } else {
        hscrf_fwd_fb<<<B, 64, 0, stream>>>(scores, mask, out, B);
    }
}

// Round 2
// 210.439 us; speedup vs baseline: 1.0022x; 1.0022x over previous
//
#include <hip/hip_runtime.h>
#include <math.h>

#define LL 128
#define TT 11
#define NP 121            // T*T (y, y_prev) pairs
#define KK 7
#define GS 20             // sp group stride (floats); group g at [g*20 .. g*20+10], pad at +11
#define SPW 240           // 11 groups*20 + dummy slots 220..226

#define LOG2E 1.4426950408889634f
#define LN2   0.6931471805599453f

__device__ __forceinline__ float fast_exp2(float x) { return __builtin_amdgcn_exp2f(x); }
__device__ __forceinline__ float fast_log2(float x) { return __builtin_amdgcn_logf(x); }
#if __has_builtin(__builtin_amdgcn_rcpf)
__device__ __forceinline__ float fast_rcp(float x) { return __builtin_amdgcn_rcpf(x); }
#else
__device__ __forceinline__ float fast_rcp(float x) { return 1.0f / x; }
#endif
__device__ __forceinline__ float rfl(float x) {
    return __int_as_float(__builtin_amdgcn_readfirstlane(__float_as_int(x)));
}
__device__ __forceinline__ void cfence() { __builtin_amdgcn_wave_barrier(); }

// ---------------------------------------------------------------------------
// Fused semi-CRF forward DP. NO WORKSPACE: the 507 MB ws re-poison fill
// (~75+ us/iter, billed to dur_us) was the real cost of the prep+dp split.
//
// One wave per batch element. Linear-domain recurrence (same math as the
// previous hscrf_dp, which passed with absmax 0):
//   window W[k][yp] = exp2(alpha2[j] - C), j = i-7+k
//   phase 1: s(y,yp) = sum_k E[k]*W[k]   (7-FMA tree, E = exp2(score*LOG2E))
//   phase 2: S(y) = sum_yp s(y,yp) via the sp LDS round trip
//   rescale: W' = shift(W, S)*r, r = rcp(S(0))  -- zero transcendentals on
//   the serial chain. C (running log2 scale) maintained off-chain.
//
// E is produced in-register instead of via a prep kernel + global E array:
//   - raw scores for pane p are global-loaded with LEAD 4 (at step p-4),
//     4-pane register rotation rA..rD (fallback-proven pattern);
//   - conversion exp2(raw*LOG2E) happens with LAG 2 (at step p-2), so the
//     vmcnt wait for the raws overlaps the phase-2 LDS read latency;
//   - j<0 masking applied at convert time (select AFTER exp2, so no vmcnt
//     wait at load-issue time), E=0 matches exp2(MASK) underflow semantics.
// Two E buffers (eX, eY) swap roles each step: phase 1 reads cur, convert
// writes E(i+2) into cur's storage after its last use.
// ---------------------------------------------------------------------------
__global__ __launch_bounds__(64, 1) void hscrf_fused(const float* __restrict__ scores,
                                                     const int* __restrict__ mask,
                                                     float* __restrict__ out,
                                                     int n_batch)
{
    const int l = threadIdx.x;
    const int b = blockIdx.x;
    if (b >= n_batch) return;

    __shared__ __align__(64) float sp[SPW];

    const int o1  = l + 64;
    const int o1c = (o1 < NP) ? o1 : 0;
    const int y0 = l / TT,   yp0 = l % TT;
    const int y1 = o1c / TT, yp1 = o1c % TT;
    const int e0 = yp0 * TT + y0;                         // score offset in NP block
    const int e1 = yp1 * TT + y1;
    const int i0w = y0 * GS + yp0;                        // phase-1 write slots
    const int i1w = (o1 < NP) ? (y1 * GS + yp1) : (220 + (l - 57));

    if (l < TT) sp[l * GS + 11] = 0.0f;                   // zero pad slot for b128 phase-2

    const int mb = mask[b];
    const float* sb = scores + (size_t)b * (size_t)(LL * LL * NP);

    // Raw score panes (4-rotation, lead 4) and linear E panes (2, swap).
    float rA0[KK], rA1[KK], rB0[KK], rB1[KK];
    float rC0[KK], rC1[KK], rD0[KK], rD1[KK];
    float eX0[KK], eX1[KK], eY0[KK], eY1[KK];

    auto load_pane = [&](int p, float (&L0)[KK], float (&L1)[KK]) {
#pragma unroll
        for (int k = 0; k < KK; ++k) {
            const int j  = p - KK + k;
            const int jc = j < 0 ? 0 : j;
            const size_t base = ((size_t)jc * LL + (size_t)(p - 1)) * NP;
            L0[k] = sb[base + e0];                        // raw loads only; no select
            L1[k] = sb[base + e1];                        // here (keeps vmcnt wait at use)
        }
    };

    // exp2 + j<0 masking; select after exp2 so the vmcnt wait lands here (lag 2).
    auto convert = [&](int p, const float (&R0)[KK], const float (&R1)[KK],
                       float (&D0)[KK], float (&D1)[KK]) {
#pragma unroll
        for (int k = 0; k < KK; ++k) {
            const float ev0 = fast_exp2(R0[k] * LOG2E);
            const float ev1 = fast_exp2(R1[k] * LOG2E);
            const bool ok = (p - KK + k) >= 0;
            D0[k] = ok ? ev0 : 0.0f;
            D1[k] = ok ? ev1 : 0.0f;
        }
    };

    // Linear-domain windows. Row 0: start state (yp==10) = 1, others 0
    // (= exp2(NEG) which underflows to 0 in fp32, same as the reference).
    float W0[KK], W1[KK];
#pragma unroll
    for (int k = 0; k < KK; ++k) { W0[k] = 0.0f; W1[k] = 0.0f; }
    W0[KK - 1] = (yp0 == TT - 1) ? 1.0f : 0.0f;
    W1[KK - 1] = (yp1 == TT - 1) ? 1.0f : 0.0f;

    float Cc = 0.0f;       // running log2 scale: alpha2[i][y] = Cc + log2(S_i(y))
    float saved = 0.0f;

    // Prologue: panes 1..4 in flight; convert 1 -> eX, 2 -> eY (one-time stalls).
    load_pane(1, rA0, rA1); load_pane(2, rB0, rB1);
    load_pane(3, rC0, rC1); load_pane(4, rD0, rD1);
    convert(1, rA0, rA1, eX0, eX1);
    convert(2, rB0, rB1, eY0, eY1);

    auto body = [&](int i, bool do_load, bool do_conv,
                    float (&EC0)[KK], float (&EC1)[KK],     // cur E(i); also convert dst
                    float (&LT0)[KK], float (&LT1)[KK],     // load target: raw pane i+4
                    float (&RS0)[KK], float (&RS1)[KK]) {   // convert src: raw pane i+2
        // ---- phase 1: 7 FMAs per pair (tree), sp write ----
        float p0 = fmaf(EC0[0], W0[0], EC0[1] * W0[1]);
        float q0 = fmaf(EC0[2], W0[2], EC0[3] * W0[3]);
        float u0 = fmaf(EC0[4], W0[4], EC0[5] * W0[5]);
        float s0 = (p0 + q0) + fmaf(EC0[6], W0[6], u0);
        float p1 = fmaf(EC1[0], W1[0], EC1[1] * W1[1]);
        float q1 = fmaf(EC1[2], W1[2], EC1[3] * W1[3]);
        float u1 = fmaf(EC1[4], W1[4], EC1[5] * W1[5]);
        float s1 = (p1 + q1) + fmaf(EC1[6], W1[6], u1);
        sp[i0w] = s0;
        sp[i1w] = s1;

        cfence();                      // DS pipe in-order per wave

        // ---- phase 2 reads (chain-critical; ~120 cyc LDS latency) ----
        const float4 qa0 = *(const float4*)(sp + yp0 * GS);
        const float4 qb0 = *(const float4*)(sp + yp0 * GS + 4);
        const float4 qc0 = *(const float4*)(sp + yp0 * GS + 8);   // pad=0
        const float4 qa1 = *(const float4*)(sp + yp1 * GS);
        const float4 qb1 = *(const float4*)(sp + yp1 * GS + 4);
        const float4 qc1 = *(const float4*)(sp + yp1 * GS + 8);

        // ---- off-chain: issue raw loads (lead 4), convert pane i+2 (lag 2).
        // The convert's vmcnt wait overlaps the phase-2 lgkm wait above.
        if (do_load) load_pane(i + 4, LT0, LT1);
        if (do_conv) convert(i + 2, RS0, RS1, EC0, EC1);

        // ---- phase-2 sums ----
        const float SA = (((qa0.x + qa0.y) + (qa0.z + qa0.w)) +
                          ((qb0.x + qb0.y) + (qb0.z + qb0.w))) +
                         ((qc0.x + qc0.y) + (qc0.z + qc0.w));
        const float SB = (((qa1.x + qa1.y) + (qa1.z + qa1.w)) +
                          ((qb1.x + qb1.y) + (qb1.z + qb1.w))) +
                         ((qc1.x + qc1.y) + (qc1.z + qc1.w));

        // ---- rescale: r = 1/S(0) (lane 0 has yp0==0) ----
        const float s0u = rfl(SA);
        const float r = fast_rcp(s0u);

        saved = (i == mb) ? Cc + fast_log2(SA) : saved;   // alpha2[i][yp0], off-chain
        Cc += fast_log2(s0u);                             // off-chain

#pragma unroll
        for (int k = 0; k < KK - 1; ++k) { W0[k] = W0[k + 1] * r; W1[k] = W1[k + 1] * r; }
        W0[KK - 1] = SA * r;
        W1[KK - 1] = SB * r;

        cfence();                      // order phase-2 reads before next sp writes
    };

    // Main loop: steps 1..124 (load pane i+4 valid through step 124 -> pane 128).
    // Pane p lives in raw slot p%4 (A=1,B=2,C=3,D=0); E parity: odd->eX, even->eY.
    for (int i = 1; i <= LL - 4; i += 4) {
        body(i,     true, true, eX0, eX1, rA0, rA1, rC0, rC1);
        body(i + 1, true, true, eY0, eY1, rB0, rB1, rD0, rD1);
        body(i + 2, true, true, eX0, eX1, rC0, rC1, rA0, rA1);
        body(i + 3, true, true, eY0, eY1, rD0, rD1, rB0, rB1);
    }
    // Tail: steps 125..128 (no loads; converts for 127,128 then none).
    body(LL - 3, false, true,  eX0, eX1, rA0, rA1, rC0, rC1);   // conv pane 127 (in C)
    body(LL - 2, false, true,  eY0, eY1, rB0, rB1, rD0, rD1);   // conv pane 128 (in D)
    body(LL - 1, false, false, eX0, eX1, rA0, rA1, rA0, rA1);
    body(LL,     false, false, eY0, eY1, rB0, rB1, rB0, rB1);

    if (l == TT - 2) {                 // lane 9: yp0 == stop_id = 9
        atomicAdd(out, saved * LN2);   // back to natural log
    }
}

extern "C" void kernel_launch(void* const* d_in, const int* in_sizes, int n_in,
                              void* d_out, int out_size, void* d_ws, size_t ws_size,
                              hipStream_t stream) {
    const float* scores = (const float*)d_in[0];
    const int*   mask   = (const int*)d_in[1];
    float* out = (float*)d_out;
    const int B = in_sizes[1];   // 16

    hipMemsetAsync(out, 0, sizeof(float) * out_size, stream);

    // No workspace use: avoids the ws_size-proportional re-poison fill
    // (~507 MB, ~75+ us) that dominated the measured iteration time.
    (void)d_ws; (void)ws_size;

    hscrf_fused<<<B, 64, 0, stream>>>(scores, mask, out, B);
}